// Round 6
// baseline (680.687 us; speedup 1.0000x reference)
//
#include <hip/hip_runtime.h>
#include <hip/hip_bf16.h>

#define NHD 16          // NH
#define NKVH 8          // NKV
#define HDIM 256        // HD
#define TSEQ 2048       // T
#define BATCH 2         // B

typedef unsigned int   u32;
typedef unsigned short u16;

typedef __attribute__((ext_vector_type(8))) short bf16x8;
typedef __attribute__((ext_vector_type(4))) float floatx4;

__device__ inline u32 cvt2bf(float lo, float hi) {
  u32 r;
  asm("v_cvt_pk_bf16_f32 %0, %1, %2" : "=v"(r) : "v"(lo), "v"(hi));
  return r;
}
__device__ inline u16 f2bf(float f) {
  union { float f; u32 i; } v; v.f = f;
  u32 r = v.i + 0x7fffu + ((v.i >> 16) & 1u);
  return (u16)(r >> 16);
}
__device__ inline float bf2f(u16 u) {
  union { u32 i; float f; } v; v.i = ((u32)u) << 16; return v.f;
}
__device__ inline float fexp2(float x) {
  float r; asm("v_exp_f32 %0, %1" : "=v"(r) : "v"(x)); return r;
}
__device__ inline float frcp(float x) {
  float r; asm("v_rcp_f32 %0, %1" : "=v"(r) : "v"(x)); return r;
}

typedef const __attribute__((address_space(1))) u32* gptr_t;
typedef __attribute__((address_space(3))) u32* lptr_t;
__device__ inline void gl_lds16(const void* g, void* l) {
  __builtin_amdgcn_global_load_lds((gptr_t)g, (lptr_t)l, 16, 0, 0);
}

// ---------------------------------------------------------------------------
// Transpose + convert: fp32 in[R][Cc] -> bf16 out[Cc][R].  64x64 tiles.
// ---------------------------------------------------------------------------
__global__ __launch_bounds__(256) void tconv_k(
    const float* __restrict__ in, u16* __restrict__ out, int R, int Cc)
{
  __shared__ float tile[64][65];
  const int r0 = blockIdx.y * 64, c0 = blockIdx.x * 64;
  const int tr = threadIdx.x >> 4;          // 0..15
  const int tc = (threadIdx.x & 15) * 4;    // 0,4,..,60
#pragma unroll
  for (int j = 0; j < 4; ++j) {
    float4 v = *(const float4*)(in + (size_t)(r0 + tr + j * 16) * Cc + c0 + tc);
    tile[tr + j * 16][tc + 0] = v.x;
    tile[tr + j * 16][tc + 1] = v.y;
    tile[tr + j * 16][tc + 2] = v.z;
    tile[tr + j * 16][tc + 3] = v.w;
  }
  __syncthreads();
#pragma unroll
  for (int j = 0; j < 4; ++j) {
    int c = tr + j * 16;
    u16 o[4];
#pragma unroll
    for (int i = 0; i < 4; ++i) o[i] = f2bf(tile[tc + i][c]);
    *(uint2*)(out + (size_t)(c0 + c) * R + r0 + tc) = *(const uint2*)o;
  }
}

// ---------------------------------------------------------------------------
// Elementwise fp32 -> bf16 convert (X): 8 elems/thread.
// ---------------------------------------------------------------------------
__global__ __launch_bounds__(256) void xconv_k(
    const float* __restrict__ in, u16* __restrict__ out)
{
  size_t i = (size_t)blockIdx.x * 256 + threadIdx.x;
  float4 a = *(const float4*)(in + i * 8);
  float4 b = *(const float4*)(in + i * 8 + 4);
  uint4 o;
  o.x = cvt2bf(a.x, a.y); o.y = cvt2bf(a.z, a.w);
  o.z = cvt2bf(b.x, b.y); o.w = cvt2bf(b.z, b.w);
  *(uint4*)(out + i * 8) = o;
}

// ---------------------------------------------------------------------------
// GEMM BMx256 tile (BM=256 or 128), BK=64, 8 waves (2m x 4n).  A bf16 [M][K],
// B bf16 transposed [N][K].  Double-buffered linear LDS via global_load_lds,
// pre-swizzled source, counted vmcnt.  4-cluster phase split per K-step:
// STAGE_A -> vmcnt(AI) -> bar -> MFMA(ks0) -> STAGE_B -> MFMA(ks1) -> bar.
// ---------------------------------------------------------------------------
template<int EPI, int BM>
__global__ __launch_bounds__(512, 2) void gemm256_k(
    const u16* __restrict__ Ab, const u16* __restrict__ BTp,
    void* __restrict__ Op, int M, int N, int K)
{
  constexpr int NI = BM / 32;        // acc rows per wave
  constexpr int AI = BM / 64;        // A gl_lds instrs per wave
  __shared__ u16 LA[2][BM * 64];
  __shared__ u16 LB[2][256 * 64];
  const int t = threadIdx.x;
  const int lane = t & 63, wave = t >> 6;        // 8 waves
  const int lg = lane >> 4, l15 = lane & 15;
  const int wm = wave >> 2, wn = wave & 3;       // 2 x 4
  const int mtiles = M / BM;
  const int mt = (int)blockIdx.x % mtiles, nt = (int)blockIdx.x / mtiles;
  const int m0 = mt * BM, n0 = nt << 8;

  const int arow = wave * (BM / 8) + (lane >> 3);
  const int ska  = ((lane & 7) ^ (arow & 7)) << 3;
  const int brow = wave * 32 + (lane >> 3);
  const int skb  = ((lane & 7) ^ (brow & 7)) << 3;
  const u16* Ag = Ab  + (size_t)(m0 + arow) * K + ska;
  const u16* Bg = BTp + (size_t)(n0 + brow) * K + skb;

  auto STAGE_A = [&](int k0, int sel) {
#pragma unroll
    for (int q = 0; q < AI; ++q)
      gl_lds16(Ag + k0 + (size_t)q * 8 * K, &LA[sel][(wave * (BM / 8) + q * 8) * 64]);
  };
  auto STAGE_B = [&](int k0, int sel) {
#pragma unroll
    for (int q = 0; q < 4; ++q)
      gl_lds16(Bg + k0 + (size_t)q * 8 * K, &LB[sel][(wave * 32 + q * 8) * 64]);
  };

  floatx4 acc[NI][4];
#pragma unroll
  for (int i = 0; i < NI; ++i)
#pragma unroll
    for (int j = 0; j < 4; ++j) acc[i][j] = (floatx4){0.f, 0.f, 0.f, 0.f};

  STAGE_A(0, 0);
  STAGE_B(0, 0);
  const int KT = K >> 6;
  for (int kt = 0; kt < KT; ++kt) {
    const int sel = kt & 1;
    if (kt + 1 < KT) {
      STAGE_A((kt + 1) << 6, sel ^ 1);
      if constexpr (BM == 256) asm volatile("s_waitcnt vmcnt(4)" ::: "memory");
      else                     asm volatile("s_waitcnt vmcnt(2)" ::: "memory");
    } else {
      asm volatile("s_waitcnt vmcnt(0)" ::: "memory");
    }
    __builtin_amdgcn_s_barrier();
    __builtin_amdgcn_sched_barrier(0);

    // ---- cluster 1: ks = 0 ----
    __builtin_amdgcn_s_setprio(1);
    {
      const int c = lg;                          // 0..3
      bf16x8 bfv[4];
#pragma unroll
      for (int j = 0; j < 4; ++j) {
        int row = wn * 64 + (j << 4) + l15;
        bfv[j] = *(const bf16x8*)(&LB[sel][row * 64 + ((c ^ (row & 7)) << 3)]);
      }
#pragma unroll
      for (int i = 0; i < NI; ++i) {
        int row = wm * (BM / 2) + (i << 4) + l15;
        bf16x8 af = *(const bf16x8*)(&LA[sel][row * 64 + ((c ^ (row & 7)) << 3)]);
#pragma unroll
        for (int j = 0; j < 4; ++j)
          acc[i][j] = __builtin_amdgcn_mfma_f32_16x16x32_bf16(af, bfv[j], acc[i][j], 0, 0, 0);
      }
    }
    __builtin_amdgcn_s_setprio(0);

    // ---- stage B of next tile between the clusters ----
    if (kt + 1 < KT) STAGE_B((kt + 1) << 6, sel ^ 1);

    // ---- cluster 2: ks = 1 ----
    __builtin_amdgcn_s_setprio(1);
    {
      const int c = 4 + lg;                      // 4..7
      bf16x8 bfv[4];
#pragma unroll
      for (int j = 0; j < 4; ++j) {
        int row = wn * 64 + (j << 4) + l15;
        bfv[j] = *(const bf16x8*)(&LB[sel][row * 64 + ((c ^ (row & 7)) << 3)]);
      }
#pragma unroll
      for (int i = 0; i < NI; ++i) {
        int row = wm * (BM / 2) + (i << 4) + l15;
        bf16x8 af = *(const bf16x8*)(&LA[sel][row * 64 + ((c ^ (row & 7)) << 3)]);
#pragma unroll
        for (int j = 0; j < 4; ++j)
          acc[i][j] = __builtin_amdgcn_mfma_f32_16x16x32_bf16(af, bfv[j], acc[i][j], 0, 0, 0);
      }
    }
    __builtin_amdgcn_s_setprio(0);
    __builtin_amdgcn_s_barrier();
  }

#pragma unroll
  for (int i = 0; i < NI; ++i) {
#pragma unroll
    for (int j = 0; j < 4; ++j) {
#pragma unroll
      for (int r = 0; r < 4; ++r) {
        int m = m0 + wm * (BM / 2) + (i << 4) + (lg << 2) + r;
        int n = n0 + wn * 64 + (j << 4) + l15;
        float v = acc[i][j][r];
        int bb = m >> 11, tt = m & 2047;
        if (EPI == 0) {
          ((float*)Op)[(size_t)m * N + n] = v;
        } else if (EPI == 1) {
          int h = n >> 8, d = n & 255;
          ((u16*)Op)[(((size_t)bb * NHD + h) * TSEQ + tt) * HDIM + d] = f2bf(v);
        } else {   // EPI 3: fused KV
          if (n < 2048) {
            int h = n >> 8, d = n & 255;
            ((u16*)Op)[(((size_t)bb * NKVH + h) * TSEQ + tt) * HDIM + d] = f2bf(v);
          } else {
            int n2 = n - 2048;
            int h = n2 >> 8, d = n2 & 255;
            ((u16*)Op)[8388608u + (((size_t)bb * NKVH + h) * HDIM + d) * TSEQ + tt] = f2bf(v);
          }
        }
      }
    }
  }
}

// ---------------------------------------------------------------------------
// RoPE in-place on [b][h][t][256] bf16: pair (d, d+128)
// ---------------------------------------------------------------------------
__global__ __launch_bounds__(256) void rope_k(u16* buf) {
  size_t idx = (size_t)blockIdx.x * 256 + threadIdx.x;
  int d = (int)(idx & 127);
  size_t rest = idx >> 7;               // (b*nheads + h)*T + t
  int tt = (int)(rest & (TSEQ - 1));
  float invf = exp2f(-(float)d * 0.103810253f);   // log2(10000)/128
  float th = (float)tt * invf;
  float sn, cs;
  sincosf(th, &sn, &cs);
  size_t base = rest * HDIM;
  float x1 = bf2f(buf[base + d]);
  float x2 = bf2f(buf[base + d + 128]);
  buf[base + d]       = f2bf(x1 * cs - x2 * sn);
  buf[base + d + 128] = f2bf(x2 * cs + x1 * sn);
}

// ---------------------------------------------------------------------------
// Causal flash attention, tanh softcap with fixed max = 50 in exp2 domain:
// p = exp2(C2 * rcp(1 + exp2(sa*C1))).  GQA h-merge: one block = BOTH heads
// of a KV group -> each staged K/V tile feeds 2x the MFMA work.
// 4 waves x 16 q rows (QBLK=64), KVBLK=32, dbuf LDS via global_load_lds
// (pre-swizzled source), counted vmcnt(8).  Grid: x=(hkv,b)=16, y=qt desc.
// ---------------------------------------------------------------------------
__global__ __launch_bounds__(256, 2) void attn_k(
    const u16* __restrict__ Q, const u16* __restrict__ Kb,
    const u16* __restrict__ Vt, u16* __restrict__ Y)
{
  __shared__ u16 Ks2[2][32 * 256];   // [s][d], 512B rows, src-swizzled
  __shared__ u16 Vs2[2][256 * 32];   // [d][s], 64B rows, src-swizzled
  __shared__ u16 Ps[4 * 16 * 32];    // per-wave [q16][s32], 64B rows
  __shared__ float Ls[4][2][16];
  const int t = threadIdx.x, lane = t & 63, w = t >> 6;
  const int lg = lane >> 4, l15 = lane & 15;
  const int qt = 31 - (int)blockIdx.y;                   // big blocks first
  const int hkv = (int)blockIdx.x >> 1, b = (int)blockIdx.x & 1;

  const u16* Kg = Kb + ((size_t)(b * NKVH + hkv)) * TSEQ * HDIM;  // [s][d]
  const u16* Vg = Vt + ((size_t)(b * NKVH + hkv)) * HDIM * TSEQ;  // [d][s]

  // pre-swizzled per-lane source offsets; LDS dest linear.
  int koff[4], voff[4];
#pragma unroll
  for (int q = 0; q < 4; ++q) {
    int krow = w * 8 + q * 2 + (lane >> 5);
    int kcc  = lane & 31;
    koff[q] = krow * 256 + ((kcc ^ (krow & 7)) << 3);
    int vd  = w * 64 + q * 16 + (lane >> 2);
    voff[q] = vd * TSEQ + (((lane & 3) ^ ((vd >> 2) & 3)) << 3);
  }

  auto STAGE = [&](int st, int sel) {
    const u16* kbase = Kg + (size_t)st * (32 * 256);
    const u16* vbase = Vg + st * 32;
#pragma unroll
    for (int q = 0; q < 4; ++q)
      gl_lds16(kbase + koff[q], &Ks2[sel][(w * 8 + q * 2) * 256]);
#pragma unroll
    for (int q = 0; q < 4; ++q)
      gl_lds16(vbase + voff[q], &Vs2[sel][(w * 64 + q * 16) * 32]);
  };

  // Q fragments for BOTH heads of the group
  bf16x8 qf[2][8];
#pragma unroll
  for (int u = 0; u < 2; ++u) {
    const u16* Qg = Q + (((size_t)(b * NHD + 2 * hkv + u)) * TSEQ +
                         qt * 64 + w * 16 + l15) * HDIM;
#pragma unroll
    for (int ks = 0; ks < 8; ++ks)
      qf[u][ks] = *(const bf16x8*)(Qg + ks * 32 + lg * 8);
  }

  floatx4 accY[2][16];
#pragma unroll
  for (int u = 0; u < 2; ++u)
#pragma unroll
    for (int i = 0; i < 16; ++i) accY[u][i] = (floatx4){0.f, 0.f, 0.f, 0.f};
  float rsum[2] = {0.f, 0.f};

  const int qglob = qt * 64 + w * 16 + l15;
  const int qmaxw = qt * 64 + w * 16 + 15;
  const int nst = 2 * qt + 2;
  const int fps = (l15 ^ (l15 >> 2)) & 3;      // Ps bank-spread term

  STAGE(0, 0);
  for (int st = 0; st < nst; ++st) {
    const int sel = st & 1;
    if (st + 1 < nst) {
      STAGE(st + 1, sel ^ 1);
      asm volatile("s_waitcnt vmcnt(8)" ::: "memory");
    } else {
      asm volatile("s_waitcnt vmcnt(0)" ::: "memory");
    }
    __builtin_amdgcn_s_barrier();
    __builtin_amdgcn_sched_barrier(0);

    if (st * 32 <= qmaxw) {
      __builtin_amdgcn_s_setprio(1);
#pragma unroll
      for (int u = 0; u < 2; ++u) {
        // --- QK^T (swapped) + softcap + causal + P write ---
#pragma unroll
        for (int stile = 0; stile < 2; ++stile) {
          floatx4 sa = (floatx4){0.f, 0.f, 0.f, 0.f};
#pragma unroll
          for (int ks = 0; ks < 8; ++ks) {
            int row = (stile << 4) + l15;
            int c = (ks << 2) + lg;
            bf16x8 kf = *(const bf16x8*)((const char*)Ks2[sel] +
                          row * 512 + ((c ^ (row & 7)) << 4));
            sa = __builtin_amdgcn_mfma_f32_16x16x32_bf16(kf, qf[u][ks], sa, 0, 0, 0);
          }
          int sbase = st * 32 + (stile << 4) + (lg << 2);
          float p[4];
#pragma unroll
          for (int r = 0; r < 4; ++r) {
            float uu = fexp2(sa[r] * 0.0036067376f);        // exp2(z/25*log2e)
            float pv = fexp2(-144.26950408f * frcp(uu + 1.0f));
            pv = (sbase + r <= qglob) ? pv : 0.0f;
            p[r] = pv;
            rsum[u] += pv;
          }
          uint2 pw;
          pw.x = cvt2bf(p[0], p[1]);
          pw.y = cvt2bf(p[2], p[3]);
          int o = (stile << 5) + (lg << 3);
          int gran = (o >> 4) ^ fps;
          *(uint2*)((char*)Ps + (w << 10) + l15 * 64 + (gran << 4) + (o & 15)) = pw;
        }
        // --- PV ---
        {
          bf16x8 pf = *(const bf16x8*)((const char*)Ps + (w << 10) + l15 * 64 +
                        ((lg ^ fps) << 4));
#pragma unroll
          for (int dt = 0; dt < 16; ++dt) {
            int row = (dt << 4) + l15;
            bf16x8 vf = *(const bf16x8*)((const char*)Vs2[sel] +
                          row * 64 + ((lg ^ ((row >> 2) & 3)) << 4));
            accY[u][dt] = __builtin_amdgcn_mfma_f32_16x16x32_bf16(pf, vf, accY[u][dt], 0, 0, 0);
          }
        }
      }
      __builtin_amdgcn_s_setprio(0);
    }
    __builtin_amdgcn_s_barrier();
  }

#pragma unroll
  for (int u = 0; u < 2; ++u) {
    float rs = rsum[u];
    rs += __shfl_xor(rs, 16);
    rs += __shfl_xor(rs, 32);
    if (lane < 16) Ls[w][u][l15] = rs;
  }
  __syncthreads();
#pragma unroll
  for (int u = 0; u < 2; ++u) {
    float inv[4];
#pragma unroll
    for (int r = 0; r < 4; ++r) inv[r] = 1.0f / Ls[w][u][(lg << 2) + r];
    u16* Yg = Y + ((size_t)(b * TSEQ + qt * 64 + w * 16)) * (NHD * HDIM) +
              (2 * hkv + u) * HDIM;
#pragma unroll
    for (int dt = 0; dt < 16; ++dt)
#pragma unroll
      for (int r = 0; r < 4; ++r)
        Yg[(size_t)((lg << 2) + r) * (NHD * HDIM) + (dt << 4) + l15] =
            f2bf(accY[u][dt][r] * inv[r]);
  }
}

// ---------------------------------------------------------------------------
extern "C" void kernel_launch(void* const* d_in, const int* in_sizes, int n_in,
                              void* d_out, int out_size, void* d_ws, size_t ws_size,
                              hipStream_t stream) {
  const float* X  = (const float*)d_in[0];
  const float* Wq = (const float*)d_in[1];
  const float* Wk = (const float*)d_in[2];
  const float* Wv = (const float*)d_in[3];
  const float* Wo = (const float*)d_in[4];
  float* out = (float*)d_out;

  u16* ws   = (u16*)d_ws;
  u16* XB   = ws;                 // [4096][2048] bf16        8,388,608
  u16* WT   = ws + 8388608;       // WqT / WkvT [4096][2048]  8,388,608
  u16* Qb   = ws + 16777216;      // [B][NH][T][HD]           16,777,216
  u16* KVb  = ws + 33554432;      // K [B][NKV][T][HD] + V^T  16,777,216
  u16* Yb   = ws;                 // [B*T][NH*HD] (over XB+WT, dead by then)
  u16* WoT  = ws + 16777216;      // [2048][4096] (over Qb, dead after attn)

  dim3 blk(256);
  xconv_k<<<dim3(4096), blk, 0, stream>>>(X, XB);
  tconv_k<<<dim3(64, 32), blk, 0, stream>>>(Wq, WT, 2048, 4096);
  gemm256_k<1, 256><<<dim3(16 * 16), dim3(512), 0, stream>>>(XB, WT, Qb, 4096, 4096, 2048);
  tconv_k<<<dim3(32, 32), blk, 0, stream>>>(Wk, WT, 2048, 2048);
  tconv_k<<<dim3(32, 32), blk, 0, stream>>>(Wv, WT + (size_t)2048 * 2048, 2048, 2048);
  gemm256_k<3, 256><<<dim3(16 * 16), dim3(512), 0, stream>>>(XB, WT, KVb, 4096, 4096, 2048);
  rope_k<<<dim3((BATCH * NHD  * TSEQ * 128) / 256), blk, 0, stream>>>(Qb);
  rope_k<<<dim3((BATCH * NKVH * TSEQ * 128) / 256), blk, 0, stream>>>(KVb);
  attn_k<<<dim3(16, 32), blk, 0, stream>>>(Qb, KVb, KVb + 8388608, Yb);
  tconv_k<<<dim3(32, 64), blk, 0, stream>>>(Wo, WoT, 4096, 2048);
  gemm256_k<0, 128><<<dim3(32 * 8), dim3(512), 0, stream>>>(Yb, WoT, out, 4096, 2048, 4096);
}

// Round 7
// 512.042 us; speedup vs baseline: 1.3294x; 1.3294x over previous
//
#include <hip/hip_runtime.h>
#include <hip/hip_bf16.h>

#define NHD 16          // NH
#define NKVH 8          // NKV
#define HDIM 256        // HD
#define TSEQ 2048       // T
#define BATCH 2         // B

typedef unsigned int   u32;
typedef unsigned short u16;

typedef __attribute__((ext_vector_type(8))) short bf16x8;
typedef __attribute__((ext_vector_type(4))) float floatx4;

__device__ inline u32 cvt2bf(float lo, float hi) {
  u32 r;
  asm("v_cvt_pk_bf16_f32 %0, %1, %2" : "=v"(r) : "v"(lo), "v"(hi));
  return r;
}
__device__ inline u16 f2bf(float f) {
  union { float f; u32 i; } v; v.f = f;
  u32 r = v.i + 0x7fffu + ((v.i >> 16) & 1u);
  return (u16)(r >> 16);
}
__device__ inline float bf2f(u16 u) {
  union { u32 i; float f; } v; v.i = ((u32)u) << 16; return v.f;
}
__device__ inline float fexp2(float x) {
  float r; asm("v_exp_f32 %0, %1" : "=v"(r) : "v"(x)); return r;
}
__device__ inline float frcp(float x) {
  float r; asm("v_rcp_f32 %0, %1" : "=v"(r) : "v"(x)); return r;
}

typedef const __attribute__((address_space(1))) u32* gptr_t;
typedef __attribute__((address_space(3))) u32* lptr_t;
__device__ inline void gl_lds16(const void* g, void* l) {
  __builtin_amdgcn_global_load_lds((gptr_t)g, (lptr_t)l, 16, 0, 0);
}

// ---------------------------------------------------------------------------
// Transpose + convert: fp32 in[R][Cc] -> bf16 out[Cc][R].  64x64 tiles.
// ---------------------------------------------------------------------------
__global__ __launch_bounds__(256) void tconv_k(
    const float* __restrict__ in, u16* __restrict__ out, int R, int Cc)
{
  __shared__ float tile[64][65];
  const int r0 = blockIdx.y * 64, c0 = blockIdx.x * 64;
  const int tr = threadIdx.x >> 4;          // 0..15
  const int tc = (threadIdx.x & 15) * 4;    // 0,4,..,60
#pragma unroll
  for (int j = 0; j < 4; ++j) {
    float4 v = *(const float4*)(in + (size_t)(r0 + tr + j * 16) * Cc + c0 + tc);
    tile[tr + j * 16][tc + 0] = v.x;
    tile[tr + j * 16][tc + 1] = v.y;
    tile[tr + j * 16][tc + 2] = v.z;
    tile[tr + j * 16][tc + 3] = v.w;
  }
  __syncthreads();
#pragma unroll
  for (int j = 0; j < 4; ++j) {
    int c = tr + j * 16;
    u16 o[4];
#pragma unroll
    for (int i = 0; i < 4; ++i) o[i] = f2bf(tile[tc + i][c]);
    *(uint2*)(out + (size_t)(c0 + c) * R + r0 + tc) = *(const uint2*)o;
  }
}

// ---------------------------------------------------------------------------
// Elementwise fp32 -> bf16 convert (X): 8 elems/thread.
// ---------------------------------------------------------------------------
__global__ __launch_bounds__(256) void xconv_k(
    const float* __restrict__ in, u16* __restrict__ out)
{
  size_t i = (size_t)blockIdx.x * 256 + threadIdx.x;
  float4 a = *(const float4*)(in + i * 8);
  float4 b = *(const float4*)(in + i * 8 + 4);
  uint4 o;
  o.x = cvt2bf(a.x, a.y); o.y = cvt2bf(a.z, a.w);
  o.z = cvt2bf(b.x, b.y); o.w = cvt2bf(b.z, b.w);
  *(uint4*)(out + i * 8) = o;
}

// ---------------------------------------------------------------------------
// Pipelined GEMM, m201-style 4-phase schedule.  BMx256 tile, BK=64, 8 waves
// (2m x 4n), wave out (BM/2)x64.  A bf16 [M][K], B bf16 transposed [N][K].
// LDS granule-major [g 0..7][row] per buffer: gl_lds writes 64 consecutive
// row-slots (linear), ds_read_b128 of 8-lane groups walks consecutive rows
// -> all 32 banks, conflict-free both sides, no XOR needed.
// Per K-tile: 4 phases {ds_read quadrant || issue 2 stage loads -> barrier ->
// lgkmcnt(0) -> setprio(1) 16 MFMA setprio(0) -> [p3: vmcnt(0)] -> barrier}.
// Stages always target buf[sel^1]; reads of buf[sel] protected by previous
// tile's vmcnt(0)+barrier.
// EPI 0: fp32 [M][N]; 1: Q bf16 [b][h][t][d]; 3: fused KV (K + V^T).
// ---------------------------------------------------------------------------
template<int EPI, int BM>
__global__ __launch_bounds__(512, 2) void gemmp_k(
    const u16* __restrict__ Ab, const u16* __restrict__ BTp,
    void* __restrict__ Op, int M, int N, int K)
{
  constexpr int NI   = BM / 32;      // m-frags per wave (8 or 4)
  constexpr int NH2  = NI / 2;       // m-frags per phase
  constexpr int ATOT = BM / 64;      // A stage instrs per thread per K-tile
  constexpr int ST   = ATOT + 4;     // total stage instrs per thread
  constexpr int ASZ  = BM * 64;      // u16 per A buffer
  constexpr int BSZ  = 256 * 64;     // u16 per B buffer
  __shared__ u16 LA[2 * ASZ];
  __shared__ u16 LB[2 * BSZ];
  const int t = threadIdx.x;
  const int lane = t & 63, wave = t >> 6;        // 8 waves
  const int lg = lane >> 4, l15 = lane & 15;
  const int wm = wave >> 2, wn = wave & 3;       // 2 x 4
  const int mtiles = M / BM;
  const int mt = (int)blockIdx.x % mtiles, nt = (int)blockIdx.x / mtiles;
  const int m0 = mt * BM, n0 = nt << 8;

  auto STAGE1 = [&](int idx, int k0, int sel) {
    if (idx < ATOT) {
      int gi = wave * ATOT + idx;        // 0..BM/8-1
      int g = gi & 7, rc = gi >> 3;      // granule, row-chunk
      gl_lds16(Ab + (size_t)(m0 + rc * 64 + lane) * K + k0 + g * 8,
               &LA[sel * ASZ + (g * BM + rc * 64) * 8]);
    } else {
      int gi = wave * 4 + (idx - ATOT);  // 0..31
      int g = gi & 7, rc = gi >> 3;
      gl_lds16(BTp + (size_t)(n0 + rc * 64 + lane) * K + k0 + g * 8,
               &LB[sel * BSZ + (g * 256 + rc * 64) * 8]);
    }
  };

  floatx4 acc[NI][4];
#pragma unroll
  for (int i = 0; i < NI; ++i)
#pragma unroll
    for (int j = 0; j < 4; ++j) acc[i][j] = (floatx4){0.f, 0.f, 0.f, 0.f};

#pragma unroll
  for (int idx = 0; idx < ST; ++idx) STAGE1(idx, 0, 0);
  asm volatile("s_waitcnt vmcnt(0)" ::: "memory");
  __builtin_amdgcn_s_barrier();

  const int KT = K >> 6;
  for (int kt = 0; kt < KT; ++kt) {
    const int sel = kt & 1;
    const int k1 = (kt + 1) << 6;
    bf16x8 bfv[4];
#pragma unroll
    for (int p = 0; p < 4; ++p) {
      const int ih = p & 1, ks = p >> 1;
      if (ih == 0) {
#pragma unroll
        for (int j = 0; j < 4; ++j) {
          int row = wn * 64 + (j << 4) + l15;
          bfv[j] = *(const bf16x8*)(&LB[sel * BSZ + (((ks << 2) + lg) * 256 + row) * 8]);
        }
      }
      bf16x8 af[NH2];
#pragma unroll
      for (int i = 0; i < NH2; ++i) {
        int row = wm * (BM / 2) + ((ih * NH2 + i) << 4) + l15;
        af[i] = *(const bf16x8*)(&LA[sel * ASZ + (((ks << 2) + lg) * BM + row) * 8]);
      }
      if (kt + 1 < KT) {
#pragma unroll
        for (int idx = (p * ST) >> 2; idx < ((p + 1) * ST) >> 2; ++idx)
          STAGE1(idx, k1, sel ^ 1);
      }
      __builtin_amdgcn_s_barrier();
      asm volatile("s_waitcnt lgkmcnt(0)" ::: "memory");
      __builtin_amdgcn_sched_barrier(0);
      __builtin_amdgcn_s_setprio(1);
#pragma unroll
      for (int i = 0; i < NH2; ++i)
#pragma unroll
        for (int j = 0; j < 4; ++j)
          acc[ih * NH2 + i][j] =
              __builtin_amdgcn_mfma_f32_16x16x32_bf16(af[i], bfv[j], acc[ih * NH2 + i][j], 0, 0, 0);
      __builtin_amdgcn_s_setprio(0);
      if (p == 3) asm volatile("s_waitcnt vmcnt(0)" ::: "memory");
      __builtin_amdgcn_s_barrier();
    }
  }

#pragma unroll
  for (int i = 0; i < NI; ++i) {
#pragma unroll
    for (int j = 0; j < 4; ++j) {
#pragma unroll
      for (int r = 0; r < 4; ++r) {
        int m = m0 + wm * (BM / 2) + (i << 4) + (lg << 2) + r;
        int n = n0 + wn * 64 + (j << 4) + l15;
        float v = acc[i][j][r];
        int bb = m >> 11, tt = m & 2047;
        if (EPI == 0) {
          ((float*)Op)[(size_t)m * N + n] = v;
        } else if (EPI == 1) {
          int h = n >> 8, d = n & 255;
          ((u16*)Op)[(((size_t)bb * NHD + h) * TSEQ + tt) * HDIM + d] = f2bf(v);
        } else {   // EPI 3: fused KV
          if (n < 2048) {
            int h = n >> 8, d = n & 255;
            ((u16*)Op)[(((size_t)bb * NKVH + h) * TSEQ + tt) * HDIM + d] = f2bf(v);
          } else {
            int n2 = n - 2048;
            int h = n2 >> 8, d = n2 & 255;
            ((u16*)Op)[8388608u + (((size_t)bb * NKVH + h) * HDIM + d) * TSEQ + tt] = f2bf(v);
          }
        }
      }
    }
  }
}

// ---------------------------------------------------------------------------
// RoPE in-place on [b][h][t][256] bf16: pair (d, d+128)
// ---------------------------------------------------------------------------
__global__ __launch_bounds__(256) void rope_k(u16* buf) {
  size_t idx = (size_t)blockIdx.x * 256 + threadIdx.x;
  int d = (int)(idx & 127);
  size_t rest = idx >> 7;               // (b*nheads + h)*T + t
  int tt = (int)(rest & (TSEQ - 1));
  float invf = exp2f(-(float)d * 0.103810253f);   // log2(10000)/128
  float th = (float)tt * invf;
  float sn, cs;
  sincosf(th, &sn, &cs);
  size_t base = rest * HDIM;
  float x1 = bf2f(buf[base + d]);
  float x2 = bf2f(buf[base + d + 128]);
  buf[base + d]       = f2bf(x1 * cs - x2 * sn);
  buf[base + d + 128] = f2bf(x2 * cs + x1 * sn);
}

// ---------------------------------------------------------------------------
// Causal flash attention (R5 version), tanh softcap with fixed max = 50 in
// exp2 domain: p = exp2(C2 * rcp(1 + exp2(sa*C1))).
// 4 waves x 16 q rows (QBLK=64), KVBLK=32.  68 KB LDS -> 2 blocks/CU.
// K/V double-buffered via global_load_lds w/ pre-swizzled source, vmcnt(8).
// Grid: x = (h,b), y = qt descending (LPT).
// ---------------------------------------------------------------------------
__global__ __launch_bounds__(256, 2) void attn_k(
    const u16* __restrict__ Q, const u16* __restrict__ Kb,
    const u16* __restrict__ Vt, u16* __restrict__ Y)
{
  __shared__ u16 Ks2[2][32 * 256];   // [s][d], 512B rows, src-swizzled
  __shared__ u16 Vs2[2][256 * 32];   // [d][s], 64B rows, src-swizzled
  __shared__ u16 Ps[4 * 16 * 32];    // per-wave [q16][s32], 64B rows
  __shared__ float Ls[4][16];
  const int t = threadIdx.x, lane = t & 63, w = t >> 6;
  const int lg = lane >> 4, l15 = lane & 15;
  const int qt = 31 - (int)blockIdx.y;                   // big blocks first
  const int h = (int)blockIdx.x >> 1, b = (int)blockIdx.x & 1;
  const int hkv = h >> 1;

  const u16* Kg = Kb + ((size_t)(b * NKVH + hkv)) * TSEQ * HDIM;  // [s][d]
  const u16* Vg = Vt + ((size_t)(b * NKVH + hkv)) * HDIM * TSEQ;  // [d][s]

  // pre-swizzled per-lane source offsets; LDS dest linear.
  int koff[4], voff[4];
#pragma unroll
  for (int q = 0; q < 4; ++q) {
    int krow = w * 8 + q * 2 + (lane >> 5);
    int kcc  = lane & 31;
    koff[q] = krow * 256 + ((kcc ^ (krow & 7)) << 3);
    int vd  = w * 64 + q * 16 + (lane >> 2);
    voff[q] = vd * TSEQ + (((lane & 3) ^ ((vd >> 2) & 3)) << 3);
  }

  auto STAGE = [&](int st, int sel) {
    const u16* kbase = Kg + (size_t)st * (32 * 256);
    const u16* vbase = Vg + st * 32;
#pragma unroll
    for (int q = 0; q < 4; ++q)
      gl_lds16(kbase + koff[q], &Ks2[sel][(w * 8 + q * 2) * 256]);
#pragma unroll
    for (int q = 0; q < 4; ++q)
      gl_lds16(vbase + voff[q], &Vs2[sel][(w * 64 + q * 16) * 32]);
  };

  const u16* Qg = Q + (((size_t)(b * NHD + h)) * TSEQ + qt * 64 + w * 16 + l15) * HDIM;
  bf16x8 qf[8];
#pragma unroll
  for (int ks = 0; ks < 8; ++ks) qf[ks] = *(const bf16x8*)(Qg + ks * 32 + lg * 8);

  floatx4 accY[16];
#pragma unroll
  for (int i = 0; i < 16; ++i) accY[i] = (floatx4){0.f, 0.f, 0.f, 0.f};
  float rsum = 0.f;

  const int qglob = qt * 64 + w * 16 + l15;
  const int qmaxw = qt * 64 + w * 16 + 15;
  const int nst = 2 * qt + 2;
  const int fps = (l15 ^ (l15 >> 2)) & 3;      // Ps bank-spread term

  STAGE(0, 0);
  for (int st = 0; st < nst; ++st) {
    const int sel = st & 1;
    if (st + 1 < nst) {
      STAGE(st + 1, sel ^ 1);
      asm volatile("s_waitcnt vmcnt(8)" ::: "memory");
    } else {
      asm volatile("s_waitcnt vmcnt(0)" ::: "memory");
    }
    __builtin_amdgcn_s_barrier();
    __builtin_amdgcn_sched_barrier(0);

    if (st * 32 <= qmaxw) {
      __builtin_amdgcn_s_setprio(1);
      // --- QK^T (swapped) + softcap + causal + P write ---
#pragma unroll
      for (int stile = 0; stile < 2; ++stile) {
        floatx4 sa = (floatx4){0.f, 0.f, 0.f, 0.f};
#pragma unroll
        for (int ks = 0; ks < 8; ++ks) {
          int row = (stile << 4) + l15;
          int c = (ks << 2) + lg;
          bf16x8 kf = *(const bf16x8*)((const char*)Ks2[sel] +
                        row * 512 + ((c ^ (row & 7)) << 4));
          sa = __builtin_amdgcn_mfma_f32_16x16x32_bf16(kf, qf[ks], sa, 0, 0, 0);
        }
        int sbase = st * 32 + (stile << 4) + (lg << 2);
        float p[4];
#pragma unroll
        for (int r = 0; r < 4; ++r) {
          float u = fexp2(sa[r] * 0.0036067376f);          // exp2(z/25*log2e)
          float pv = fexp2(-144.26950408f * frcp(u + 1.0f));
          pv = (sbase + r <= qglob) ? pv : 0.0f;
          p[r] = pv;
          rsum += pv;
        }
        uint2 pw;
        pw.x = cvt2bf(p[0], p[1]);
        pw.y = cvt2bf(p[2], p[3]);
        int o = (stile << 5) + (lg << 3);
        int gran = (o >> 4) ^ fps;
        *(uint2*)((char*)Ps + (w << 10) + l15 * 64 + (gran << 4) + (o & 15)) = pw;
      }
      // --- PV ---
      {
        bf16x8 pf = *(const bf16x8*)((const char*)Ps + (w << 10) + l15 * 64 +
                      ((lg ^ fps) << 4));
#pragma unroll
        for (int dt = 0; dt < 16; ++dt) {
          int row = (dt << 4) + l15;
          bf16x8 vf = *(const bf16x8*)((const char*)Vs2[sel] +
                        row * 64 + ((lg ^ ((row >> 2) & 3)) << 4));
          accY[dt] = __builtin_amdgcn_mfma_f32_16x16x32_bf16(pf, vf, accY[dt], 0, 0, 0);
        }
      }
      __builtin_amdgcn_s_setprio(0);
    }
    __builtin_amdgcn_s_barrier();
  }

  rsum += __shfl_xor(rsum, 16);
  rsum += __shfl_xor(rsum, 32);
  if (lane < 16) Ls[w][l15] = rsum;
  __syncthreads();
  float inv[4];
#pragma unroll
  for (int r = 0; r < 4; ++r) inv[r] = 1.0f / Ls[w][(lg << 2) + r];

  u16* Yg = Y + ((size_t)(b * TSEQ + qt * 64 + w * 16)) * (NHD * HDIM) + h * HDIM;
#pragma unroll
  for (int dt = 0; dt < 16; ++dt)
#pragma unroll
    for (int r = 0; r < 4; ++r)
      Yg[(size_t)((lg << 2) + r) * (NHD * HDIM) + (dt << 4) + l15] =
          f2bf(accY[dt][r] * inv[r]);
}

// ---------------------------------------------------------------------------
extern "C" void kernel_launch(void* const* d_in, const int* in_sizes, int n_in,
                              void* d_out, int out_size, void* d_ws, size_t ws_size,
                              hipStream_t stream) {
  const float* X  = (const float*)d_in[0];
  const float* Wq = (const float*)d_in[1];
  const float* Wk = (const float*)d_in[2];
  const float* Wv = (const float*)d_in[3];
  const float* Wo = (const float*)d_in[4];
  float* out = (float*)d_out;

  u16* ws   = (u16*)d_ws;
  u16* XB   = ws;                 // [4096][2048] bf16        8,388,608
  u16* WT   = ws + 8388608;       // WqT / WkvT [4096][2048]  8,388,608
  u16* Qb   = ws + 16777216;      // [B][NH][T][HD]           16,777,216
  u16* KVb  = ws + 33554432;      // K [B][NKV][T][HD] + V^T  16,777,216
  u16* Yb   = ws;                 // [B*T][NH*HD] (over XB+WT, dead by then)
  u16* WoT  = ws + 16777216;      // [2048][4096] (over Qb, dead after attn)

  dim3 blk(256);
  xconv_k<<<dim3(4096), blk, 0, stream>>>(X, XB);
  tconv_k<<<dim3(64, 32), blk, 0, stream>>>(Wq, WT, 2048, 4096);
  gemmp_k<1, 256><<<dim3(16 * 16), dim3(512), 0, stream>>>(XB, WT, Qb, 4096, 4096, 2048);
  tconv_k<<<dim3(32, 32), blk, 0, stream>>>(Wk, WT, 2048, 2048);
  tconv_k<<<dim3(32, 32), blk, 0, stream>>>(Wv, WT + (size_t)2048 * 2048, 2048, 2048);
  gemmp_k<3, 256><<<dim3(16 * 16), dim3(512), 0, stream>>>(XB, WT, KVb, 4096, 4096, 2048);
  rope_k<<<dim3((BATCH * NHD  * TSEQ * 128) / 256), blk, 0, stream>>>(Qb);
  rope_k<<<dim3((BATCH * NKVH * TSEQ * 128) / 256), blk, 0, stream>>>(KVb);
  attn_k<<<dim3(32, 32), blk, 0, stream>>>(Qb, KVb, KVb + 8388608, Yb);
  tconv_k<<<dim3(32, 64), blk, 0, stream>>>(Wo, WoT, 4096, 2048);
  gemmp_k<0, 128><<<dim3(32 * 8), dim3(512), 0, stream>>>(Yb, WoT, out, 4096, 2048, 4096);
}

// Round 8
// 462.106 us; speedup vs baseline: 1.4730x; 1.1081x over previous
//
#include <hip/hip_runtime.h>
#include <hip/hip_bf16.h>

#define NHD 16          // NH
#define NKVH 8          // NKV
#define HDIM 256        // HD
#define TSEQ 2048       // T
#define BATCH 2         // B

typedef unsigned int   u32;
typedef unsigned short u16;

typedef __attribute__((ext_vector_type(8))) short bf16x8;
typedef __attribute__((ext_vector_type(4))) float floatx4;

__device__ inline u32 cvt2bf(float lo, float hi) {
  u32 r;
  asm("v_cvt_pk_bf16_f32 %0, %1, %2" : "=v"(r) : "v"(lo), "v"(hi));
  return r;
}
__device__ inline u16 f2bf(float f) {
  union { float f; u32 i; } v; v.f = f;
  u32 r = v.i + 0x7fffu + ((v.i >> 16) & 1u);
  return (u16)(r >> 16);
}
__device__ inline float bf2f(u16 u) {
  union { u32 i; float f; } v; v.i = ((u32)u) << 16; return v.f;
}
__device__ inline float fexp2(float x) {
  float r; asm("v_exp_f32 %0, %1" : "=v"(r) : "v"(x)); return r;
}
__device__ inline float frcp(float x) {
  float r; asm("v_rcp_f32 %0, %1" : "=v"(r) : "v"(x)); return r;
}

typedef const __attribute__((address_space(1))) u32* gptr_t;
typedef __attribute__((address_space(3))) u32* lptr_t;
__device__ inline void gl_lds16(const void* g, void* l) {
  __builtin_amdgcn_global_load_lds((gptr_t)g, (lptr_t)l, 16, 0, 0);
}

// ---------------------------------------------------------------------------
// Transpose + convert: fp32 in[R][Cc] -> bf16 out[Cc][R].  64x64 tiles.
// ---------------------------------------------------------------------------
__global__ __launch_bounds__(256) void tconv_k(
    const float* __restrict__ in, u16* __restrict__ out, int R, int Cc)
{
  __shared__ float tile[64][65];
  const int r0 = blockIdx.y * 64, c0 = blockIdx.x * 64;
  const int tr = threadIdx.x >> 4;          // 0..15
  const int tc = (threadIdx.x & 15) * 4;    // 0,4,..,60
#pragma unroll
  for (int j = 0; j < 4; ++j) {
    float4 v = *(const float4*)(in + (size_t)(r0 + tr + j * 16) * Cc + c0 + tc);
    tile[tr + j * 16][tc + 0] = v.x;
    tile[tr + j * 16][tc + 1] = v.y;
    tile[tr + j * 16][tc + 2] = v.z;
    tile[tr + j * 16][tc + 3] = v.w;
  }
  __syncthreads();
#pragma unroll
  for (int j = 0; j < 4; ++j) {
    int c = tr + j * 16;
    u16 o[4];
#pragma unroll
    for (int i = 0; i < 4; ++i) o[i] = f2bf(tile[tc + i][c]);
    *(uint2*)(out + (size_t)(c0 + c) * R + r0 + tc) = *(const uint2*)o;
  }
}

// ---------------------------------------------------------------------------
// Elementwise fp32 -> bf16 convert (X): 8 elems/thread.
// ---------------------------------------------------------------------------
__global__ __launch_bounds__(256) void xconv_k(
    const float* __restrict__ in, u16* __restrict__ out)
{
  size_t i = (size_t)blockIdx.x * 256 + threadIdx.x;
  float4 a = *(const float4*)(in + i * 8);
  float4 b = *(const float4*)(in + i * 8 + 4);
  uint4 o;
  o.x = cvt2bf(a.x, a.y); o.y = cvt2bf(a.z, a.w);
  o.z = cvt2bf(b.x, b.y); o.w = cvt2bf(b.z, b.w);
  *(uint4*)(out + i * 8) = o;
}

// ---------------------------------------------------------------------------
// K-half pipelined GEMM.  BMx256 tile, 8 waves (2m x 4n), wave out (BM/2)x64.
// A bf16 [M][K], B bf16 transposed [N][K].
// Pipeline granularity = K-half (32 cols).  LDS: 4 slots, each holding one
// K-half of A (BM x 32) + B (256 x 32) in granule-major [g 0..3][row] layout
// (R7-verified conflict-free for both gl_lds writes and ds_read_b128 reads).
// Phase H: vmcnt(counted) -> barrier -> ds_read 12xb128 -> issue stage H+3 ->
// lgkmcnt(0) -> setprio(1) 32 MFMA setprio(0) -> barrier.
// Slot (H+3)&3 == (H-1)&3: its readers passed phase H-1's end barrier.
// Tail vmcnt counted exactly (2L / L / 0 by halves remaining in flight).
// EPI 0: fp32 [M][N]; 1: Q bf16 [b][h][t][d]; 3: fused KV (K + V^T).
// ---------------------------------------------------------------------------
template<int EPI, int BM>
__global__ __launch_bounds__(512, 2) void gemmp2_k(
    const u16* __restrict__ Ab, const u16* __restrict__ BTp,
    void* __restrict__ Op, int M, int N, int K)
{
  constexpr int NI  = BM / 32;       // m-frags per wave (8 or 4)
  constexpr int AIN = BM / 128;      // A stage instrs per wave per phase (2 or 1)
  constexpr int ASL = BM * 32;       // u16 per A slot
  constexpr int BSL = 256 * 32;      // u16 per B slot
  __shared__ u16 LA[4 * ASL];
  __shared__ u16 LB[4 * BSL];
  const int t = threadIdx.x;
  const int lane = t & 63, wave = t >> 6;        // 8 waves
  const int lg = lane >> 4, l15 = lane & 15;
  const int wm = wave >> 2, wn = wave & 3;       // 2 x 4
  const int mtiles = M / BM;
  // bijective XCD swizzle (grid sizes here are multiples of 8)
  const int nwg = (int)gridDim.x;
  int bid = (int)blockIdx.x;
  bid = (bid & 7) * (nwg >> 3) + (bid >> 3);
  const int mt = bid % mtiles, nt = bid / mtiles;
  const int m0 = mt * BM, n0 = nt << 8;

  const int NHALF = K >> 5;

  auto STAGE = [&](int H) {       // stage K-half H into slot H&3
    const int slot = H & 3;
    const int k0 = H << 5;
#pragma unroll
    for (int q = 0; q < AIN; ++q) {
      int idx = wave * AIN + q;              // 0..(BM/16-1)
      int g = idx & 3, rc = idx >> 2;
      gl_lds16(Ab + (size_t)(m0 + rc * 64 + lane) * K + k0 + g * 8,
               &LA[slot * ASL + (g * BM + rc * 64) * 8]);
    }
#pragma unroll
    for (int q = 0; q < 2; ++q) {
      int idx = wave * 2 + q;                // 0..15
      int g = idx & 3, rc = idx >> 2;
      gl_lds16(BTp + (size_t)(n0 + rc * 64 + lane) * K + k0 + g * 8,
               &LB[slot * BSL + (g * 256 + rc * 64) * 8]);
    }
  };

  floatx4 acc[NI][4];
#pragma unroll
  for (int i = 0; i < NI; ++i)
#pragma unroll
    for (int j = 0; j < 4; ++j) acc[i][j] = (floatx4){0.f, 0.f, 0.f, 0.f};

  STAGE(0); STAGE(1); STAGE(2);

  for (int H = 0; H < NHALF; ++H) {
    const int slot = H & 3;
    const int rem = NHALF - 1 - H;           // halves issued beyond H
    if constexpr (BM == 256) {
      if (rem >= 2)      asm volatile("s_waitcnt vmcnt(8)" ::: "memory");
      else if (rem == 1) asm volatile("s_waitcnt vmcnt(4)" ::: "memory");
      else               asm volatile("s_waitcnt vmcnt(0)" ::: "memory");
    } else {
      if (rem >= 2)      asm volatile("s_waitcnt vmcnt(6)" ::: "memory");
      else if (rem == 1) asm volatile("s_waitcnt vmcnt(3)" ::: "memory");
      else               asm volatile("s_waitcnt vmcnt(0)" ::: "memory");
    }
    __builtin_amdgcn_s_barrier();

    bf16x8 bfv[4], af[NI];
#pragma unroll
    for (int j = 0; j < 4; ++j)
      bfv[j] = *(const bf16x8*)(&LB[slot * BSL + (lg * 256 + wn * 64 + (j << 4) + l15) * 8]);
#pragma unroll
    for (int i = 0; i < NI; ++i)
      af[i] = *(const bf16x8*)(&LA[slot * ASL + (lg * BM + wm * (BM / 2) + (i << 4) + l15) * 8]);

    if (H + 3 < NHALF) STAGE(H + 3);

    asm volatile("s_waitcnt lgkmcnt(0)" ::: "memory");
    __builtin_amdgcn_sched_barrier(0);
    __builtin_amdgcn_s_setprio(1);
#pragma unroll
    for (int i = 0; i < NI; ++i)
#pragma unroll
      for (int j = 0; j < 4; ++j)
        acc[i][j] = __builtin_amdgcn_mfma_f32_16x16x32_bf16(af[i], bfv[j], acc[i][j], 0, 0, 0);
    __builtin_amdgcn_s_setprio(0);
    __builtin_amdgcn_s_barrier();
  }

#pragma unroll
  for (int i = 0; i < NI; ++i) {
#pragma unroll
    for (int j = 0; j < 4; ++j) {
#pragma unroll
      for (int r = 0; r < 4; ++r) {
        int m = m0 + wm * (BM / 2) + (i << 4) + (lg << 2) + r;
        int n = n0 + wn * 64 + (j << 4) + l15;
        float v = acc[i][j][r];
        int bb = m >> 11, tt = m & 2047;
        if (EPI == 0) {
          ((float*)Op)[(size_t)m * N + n] = v;
        } else if (EPI == 1) {
          int h = n >> 8, d = n & 255;
          ((u16*)Op)[(((size_t)bb * NHD + h) * TSEQ + tt) * HDIM + d] = f2bf(v);
        } else {   // EPI 3: fused KV
          if (n < 2048) {
            int h = n >> 8, d = n & 255;
            ((u16*)Op)[(((size_t)bb * NKVH + h) * TSEQ + tt) * HDIM + d] = f2bf(v);
          } else {
            int n2 = n - 2048;
            int h = n2 >> 8, d = n2 & 255;
            ((u16*)Op)[8388608u + (((size_t)bb * NKVH + h) * HDIM + d) * TSEQ + tt] = f2bf(v);
          }
        }
      }
    }
  }
}

// ---------------------------------------------------------------------------
// RoPE in-place on [b][h][t][256] bf16: pair (d, d+128)
// ---------------------------------------------------------------------------
__global__ __launch_bounds__(256) void rope_k(u16* buf) {
  size_t idx = (size_t)blockIdx.x * 256 + threadIdx.x;
  int d = (int)(idx & 127);
  size_t rest = idx >> 7;               // (b*nheads + h)*T + t
  int tt = (int)(rest & (TSEQ - 1));
  float invf = exp2f(-(float)d * 0.103810253f);   // log2(10000)/128
  float th = (float)tt * invf;
  float sn, cs;
  sincosf(th, &sn, &cs);
  size_t base = rest * HDIM;
  float x1 = bf2f(buf[base + d]);
  float x2 = bf2f(buf[base + d + 128]);
  buf[base + d]       = f2bf(x1 * cs - x2 * sn);
  buf[base + d + 128] = f2bf(x2 * cs + x1 * sn);
}

// ---------------------------------------------------------------------------
// Causal flash attention (R5 version), tanh softcap with fixed max = 50 in
// exp2 domain: p = exp2(C2 * rcp(1 + exp2(sa*C1))).
// 4 waves x 16 q rows (QBLK=64), KVBLK=32.  68 KB LDS -> 2 blocks/CU.
// K/V double-buffered via global_load_lds w/ pre-swizzled source, vmcnt(8).
// Grid: x = (h,b), y = qt descending (LPT).
// ---------------------------------------------------------------------------
__global__ __launch_bounds__(256, 2) void attn_k(
    const u16* __restrict__ Q, const u16* __restrict__ Kb,
    const u16* __restrict__ Vt, u16* __restrict__ Y)
{
  __shared__ u16 Ks2[2][32 * 256];   // [s][d], 512B rows, src-swizzled
  __shared__ u16 Vs2[2][256 * 32];   // [d][s], 64B rows, src-swizzled
  __shared__ u16 Ps[4 * 16 * 32];    // per-wave [q16][s32], 64B rows
  __shared__ float Ls[4][16];
  const int t = threadIdx.x, lane = t & 63, w = t >> 6;
  const int lg = lane >> 4, l15 = lane & 15;
  const int qt = 31 - (int)blockIdx.y;                   // big blocks first
  const int h = (int)blockIdx.x >> 1, b = (int)blockIdx.x & 1;
  const int hkv = h >> 1;

  const u16* Kg = Kb + ((size_t)(b * NKVH + hkv)) * TSEQ * HDIM;  // [s][d]
  const u16* Vg = Vt + ((size_t)(b * NKVH + hkv)) * HDIM * TSEQ;  // [d][s]

  // pre-swizzled per-lane source offsets; LDS dest linear.
  int koff[4], voff[4];
#pragma unroll
  for (int q = 0; q < 4; ++q) {
    int krow = w * 8 + q * 2 + (lane >> 5);
    int kcc  = lane & 31;
    koff[q] = krow * 256 + ((kcc ^ (krow & 7)) << 3);
    int vd  = w * 64 + q * 16 + (lane >> 2);
    voff[q] = vd * TSEQ + (((lane & 3) ^ ((vd >> 2) & 3)) << 3);
  }

  auto STAGE = [&](int st, int sel) {
    const u16* kbase = Kg + (size_t)st * (32 * 256);
    const u16* vbase = Vg + st * 32;
#pragma unroll
    for (int q = 0; q < 4; ++q)
      gl_lds16(kbase + koff[q], &Ks2[sel][(w * 8 + q * 2) * 256]);
#pragma unroll
    for (int q = 0; q < 4; ++q)
      gl_lds16(vbase + voff[q], &Vs2[sel][(w * 64 + q * 16) * 32]);
  };

  const u16* Qg = Q + (((size_t)(b * NHD + h)) * TSEQ + qt * 64 + w * 16 + l15) * HDIM;
  bf16x8 qf[8];
#pragma unroll
  for (int ks = 0; ks < 8; ++ks) qf[ks] = *(const bf16x8*)(Qg + ks * 32 + lg * 8);

  floatx4 accY[16];
#pragma unroll
  for (int i = 0; i < 16; ++i) accY[i] = (floatx4){0.f, 0.f, 0.f, 0.f};
  float rsum = 0.f;

  const int qglob = qt * 64 + w * 16 + l15;
  const int qmaxw = qt * 64 + w * 16 + 15;
  const int nst = 2 * qt + 2;
  const int fps = (l15 ^ (l15 >> 2)) & 3;      // Ps bank-spread term

  STAGE(0, 0);
  for (int st = 0; st < nst; ++st) {
    const int sel = st & 1;
    if (st + 1 < nst) {
      STAGE(st + 1, sel ^ 1);
      asm volatile("s_waitcnt vmcnt(8)" ::: "memory");
    } else {
      asm volatile("s_waitcnt vmcnt(0)" ::: "memory");
    }
    __builtin_amdgcn_s_barrier();
    __builtin_amdgcn_sched_barrier(0);

    if (st * 32 <= qmaxw) {
      __builtin_amdgcn_s_setprio(1);
      // --- QK^T (swapped) + softcap + causal + P write ---
#pragma unroll
      for (int stile = 0; stile < 2; ++stile) {
        floatx4 sa = (floatx4){0.f, 0.f, 0.f, 0.f};
#pragma unroll
        for (int ks = 0; ks < 8; ++ks) {
          int row = (stile << 4) + l15;
          int c = (ks << 2) + lg;
          bf16x8 kf = *(const bf16x8*)((const char*)Ks2[sel] +
                        row * 512 + ((c ^ (row & 7)) << 4));
          sa = __builtin_amdgcn_mfma_f32_16x16x32_bf16(kf, qf[ks], sa, 0, 0, 0);
        }
        int sbase = st * 32 + (stile << 4) + (lg << 2);
        float p[4];
#pragma unroll
        for (int r = 0; r < 4; ++r) {
          float u = fexp2(sa[r] * 0.0036067376f);          // exp2(z/25*log2e)
          float pv = fexp2(-144.26950408f * frcp(u + 1.0f));
          pv = (sbase + r <= qglob) ? pv : 0.0f;
          p[r] = pv;
          rsum += pv;
        }
        uint2 pw;
        pw.x = cvt2bf(p[0], p[1]);
        pw.y = cvt2bf(p[2], p[3]);
        int o = (stile << 5) + (lg << 3);
        int gran = (o >> 4) ^ fps;
        *(uint2*)((char*)Ps + (w << 10) + l15 * 64 + (gran << 4) + (o & 15)) = pw;
      }
      // --- PV ---
      {
        bf16x8 pf = *(const bf16x8*)((const char*)Ps + (w << 10) + l15 * 64 +
                      ((lg ^ fps) << 4));
#pragma unroll
        for (int dt = 0; dt < 16; ++dt) {
          int row = (dt << 4) + l15;
          bf16x8 vf = *(const bf16x8*)((const char*)Vs2[sel] +
                        row * 64 + ((lg ^ ((row >> 2) & 3)) << 4));
          accY[dt] = __builtin_amdgcn_mfma_f32_16x16x32_bf16(pf, vf, accY[dt], 0, 0, 0);
        }
      }
      __builtin_amdgcn_s_setprio(0);
    }
    __builtin_amdgcn_s_barrier();
  }

  rsum += __shfl_xor(rsum, 16);
  rsum += __shfl_xor(rsum, 32);
  if (lane < 16) Ls[w][l15] = rsum;
  __syncthreads();
  float inv[4];
#pragma unroll
  for (int r = 0; r < 4; ++r) inv[r] = 1.0f / Ls[w][(lg << 2) + r];

  u16* Yg = Y + ((size_t)(b * TSEQ + qt * 64 + w * 16)) * (NHD * HDIM) + h * HDIM;
#pragma unroll
  for (int dt = 0; dt < 16; ++dt)
#pragma unroll
    for (int r = 0; r < 4; ++r)
      Yg[(size_t)((lg << 2) + r) * (NHD * HDIM) + (dt << 4) + l15] =
          f2bf(accY[dt][r] * inv[r]);
}

// ---------------------------------------------------------------------------
extern "C" void kernel_launch(void* const* d_in, const int* in_sizes, int n_in,
                              void* d_out, int out_size, void* d_ws, size_t ws_size,
                              hipStream_t stream) {
  const float* X  = (const float*)d_in[0];
  const float* Wq = (const float*)d_in[1];
  const float* Wk = (const float*)d_in[2];
  const float* Wv = (const float*)d_in[3];
  const float* Wo = (const float*)d_in[4];
  float* out = (float*)d_out;

  u16* ws   = (u16*)d_ws;
  u16* XB   = ws;                 // [4096][2048] bf16        8,388,608
  u16* WT   = ws + 8388608;       // WqT / WkvT [4096][2048]  8,388,608
  u16* Qb   = ws + 16777216;      // [B][NH][T][HD]           16,777,216
  u16* KVb  = ws + 33554432;      // K [B][NKV][T][HD] + V^T  16,777,216
  u16* Yb   = ws;                 // [B*T][NH*HD] (over XB+WT, dead by then)
  u16* WoT  = ws + 16777216;      // [2048][4096] (over Qb, dead after attn)

  dim3 blk(256);
  xconv_k<<<dim3(4096), blk, 0, stream>>>(X, XB);
  tconv_k<<<dim3(64, 32), blk, 0, stream>>>(Wq, WT, 2048, 4096);
  gemmp2_k<1, 256><<<dim3(16 * 16), dim3(512), 0, stream>>>(XB, WT, Qb, 4096, 4096, 2048);
  tconv_k<<<dim3(32, 32), blk, 0, stream>>>(Wk, WT, 2048, 2048);
  tconv_k<<<dim3(32, 32), blk, 0, stream>>>(Wv, WT + (size_t)2048 * 2048, 2048, 2048);
  gemmp2_k<3, 256><<<dim3(16 * 16), dim3(512), 0, stream>>>(XB, WT, KVb, 4096, 4096, 2048);
  rope_k<<<dim3((BATCH * NHD  * TSEQ * 128) / 256), blk, 0, stream>>>(Qb);
  rope_k<<<dim3((BATCH * NKVH * TSEQ * 128) / 256), blk, 0, stream>>>(KVb);
  attn_k<<<dim3(32, 32), blk, 0, stream>>>(Qb, KVb, KVb + 8388608, Yb);
  tconv_k<<<dim3(32, 64), blk, 0, stream>>>(Wo, WoT, 4096, 2048);
  gemmp2_k<0, 128><<<dim3(32 * 8), dim3(512), 0, stream>>>(Yb, WoT, out, 4096, 2048, 4096);
}

// Round 9
// 444.330 us; speedup vs baseline: 1.5319x; 1.0400x over previous
//
#include <hip/hip_runtime.h>
#include <hip/hip_bf16.h>

#define NHD 16          // NH
#define NKVH 8          // NKV
#define HDIM 256        // HD
#define TSEQ 2048       // T
#define BATCH 2         // B

typedef unsigned int   u32;
typedef unsigned short u16;

typedef __attribute__((ext_vector_type(8))) short bf16x8;
typedef __attribute__((ext_vector_type(4))) float floatx4;

__device__ inline u32 cvt2bf(float lo, float hi) {
  u32 r;
  asm("v_cvt_pk_bf16_f32 %0, %1, %2" : "=v"(r) : "v"(lo), "v"(hi));
  return r;
}
__device__ inline u16 f2bf(float f) {
  union { float f; u32 i; } v; v.f = f;
  u32 r = v.i + 0x7fffu + ((v.i >> 16) & 1u);
  return (u16)(r >> 16);
}
__device__ inline float bf2f(u16 u) {
  union { u32 i; float f; } v; v.i = ((u32)u) << 16; return v.f;
}
__device__ inline float fexp2(float x) {
  float r; asm("v_exp_f32 %0, %1" : "=v"(r) : "v"(x)); return r;
}
__device__ inline float frcp(float x) {
  float r; asm("v_rcp_f32 %0, %1" : "=v"(r) : "v"(x)); return r;
}

typedef const __attribute__((address_space(1))) u32* gptr_t;
typedef __attribute__((address_space(3))) u32* lptr_t;
__device__ inline void gl_lds16(const void* g, void* l) {
  __builtin_amdgcn_global_load_lds((gptr_t)g, (lptr_t)l, 16, 0, 0);
}

// ---------------------------------------------------------------------------
// Transpose + convert: fp32 in[R][Cc] -> bf16 out[Cc][R].  64x64 tiles.
// ---------------------------------------------------------------------------
__global__ __launch_bounds__(256) void tconv_k(
    const float* __restrict__ in, u16* __restrict__ out, int R, int Cc)
{
  __shared__ float tile[64][65];
  const int r0 = blockIdx.y * 64, c0 = blockIdx.x * 64;
  const int tr = threadIdx.x >> 4;          // 0..15
  const int tc = (threadIdx.x & 15) * 4;    // 0,4,..,60
#pragma unroll
  for (int j = 0; j < 4; ++j) {
    float4 v = *(const float4*)(in + (size_t)(r0 + tr + j * 16) * Cc + c0 + tc);
    tile[tr + j * 16][tc + 0] = v.x;
    tile[tr + j * 16][tc + 1] = v.y;
    tile[tr + j * 16][tc + 2] = v.z;
    tile[tr + j * 16][tc + 3] = v.w;
  }
  __syncthreads();
#pragma unroll
  for (int j = 0; j < 4; ++j) {
    int c = tr + j * 16;
    u16 o[4];
#pragma unroll
    for (int i = 0; i < 4; ++i) o[i] = f2bf(tile[tc + i][c]);
    *(uint2*)(out + (size_t)(c0 + c) * R + r0 + tc) = *(const uint2*)o;
  }
}

// ---------------------------------------------------------------------------
// Elementwise fp32 -> bf16 convert (X): 8 elems/thread.
// ---------------------------------------------------------------------------
__global__ __launch_bounds__(256) void xconv_k(
    const float* __restrict__ in, u16* __restrict__ out)
{
  size_t i = (size_t)blockIdx.x * 256 + threadIdx.x;
  float4 a = *(const float4*)(in + i * 8);
  float4 b = *(const float4*)(in + i * 8 + 4);
  uint4 o;
  o.x = cvt2bf(a.x, a.y); o.y = cvt2bf(a.z, a.w);
  o.z = cvt2bf(b.x, b.y); o.w = cvt2bf(b.z, b.w);
  *(uint4*)(out + i * 8) = o;
}

// ---------------------------------------------------------------------------
// m201-style quadrant-phase GEMM.  256x256 tile, BK=64, 8 waves (2m x 4n),
// wave out 128x64 = 8 m-frags x 4 n-frags.  A bf16 [M][K], B bf16^T [N][K].
// LDS: 2 K-tile buffers x (A 32KB + B 32KB) = 128 KB, granule-major
// [kh*4+g][row] (R7-measured 0 bank conflicts both sides).
// Group kt = 4 phases; phase p computes m-frags {2p,2p+1} x 4 n x 2 kh
// (16 MFMA).  bfv (all 8 B frags) read once at p0 into regs; af 4/phase.
// Stage ledger (half-tile = 2 gl_lds/thread):
//   p0: A(kt+1)-lo -> oth.A (dead: last read kt-1.p3, barrier-separated)
//   p1: A(kt+1)-hi -> oth.A
//   p2: B(kt+2)-lo -> cur.B (dead after all waves pass p1 barrier)
//   p3: B(kt+2)-hi -> cur.B
// vmcnt(4) once per group at p0 (leaves B(kt+1)'s 4 loads in flight);
// vmcnt(0) at the last group.  Leads: A 3-4 phases, B 5-6 phases.
// EPI 1: Q bf16 [b][h][t][d]; 3: fused KV (K [b][h][t][d] + V^T [b][h][d][t]).
// ---------------------------------------------------------------------------
template<int EPI>
__global__ __launch_bounds__(512, 2) void gemmq_k(
    const u16* __restrict__ Ab, const u16* __restrict__ BTp,
    void* __restrict__ Op, int M, int N, int K)
{
  constexpr int BUF = 256 * 64;      // u16 per operand buffer (32 KB)
  __shared__ u16 LA[2 * BUF];
  __shared__ u16 LB[2 * BUF];
  const int t = threadIdx.x;
  const int lane = t & 63, wave = t >> 6;        // 8 waves
  const int lg = lane >> 4, l15 = lane & 15;
  const int wm = wave >> 2, wn = wave & 3;       // 2 x 4
  const int mtiles = M >> 8;
  const int mt = (int)blockIdx.x % mtiles, nt = (int)blockIdx.x / mtiles;
  const int m0 = mt << 8, n0 = nt << 8;

  // stage one half-tile (h = 0: rows 0-127, 1: rows 128-255) of tile kt.
  auto STAGE_A = [&](int kt, int h) {
    const int slot = kt & 1, k0 = kt << 6;
#pragma unroll
    for (int q = 0; q < 2; ++q) {
      int idx = wave * 2 + q;                  // 0..15
      int kh = idx >> 3, g = (idx >> 1) & 3, rc = idx & 1;
      int row = h * 128 + rc * 64;
      gl_lds16(Ab + (size_t)(m0 + row + lane) * K + k0 + kh * 32 + g * 8,
               &LA[slot * BUF + (((kh << 2) + g) * 256 + row) * 8]);
    }
  };
  auto STAGE_B = [&](int kt, int h) {
    const int slot = kt & 1, k0 = kt << 6;
#pragma unroll
    for (int q = 0; q < 2; ++q) {
      int idx = wave * 2 + q;
      int kh = idx >> 3, g = (idx >> 1) & 3, rc = idx & 1;
      int row = h * 128 + rc * 64;
      gl_lds16(BTp + (size_t)(n0 + row + lane) * K + k0 + kh * 32 + g * 8,
               &LB[slot * BUF + (((kh << 2) + g) * 256 + row) * 8]);
    }
  };

  floatx4 acc[8][4];
#pragma unroll
  for (int i = 0; i < 8; ++i)
#pragma unroll
    for (int j = 0; j < 4; ++j) acc[i][j] = (floatx4){0.f, 0.f, 0.f, 0.f};

  // prologue: A(0) both halves, B(0), B(1)  -> 12 loads/thread
  STAGE_A(0, 0); STAGE_A(0, 1);
  STAGE_B(0, 0); STAGE_B(0, 1);
  STAGE_B(1, 0); STAGE_B(1, 1);

  const int KT = K >> 6;
  for (int kt = 0; kt < KT; ++kt) {
    const int slot = kt & 1;
    bf16x8 bfv[2][4];
#pragma unroll
    for (int p = 0; p < 4; ++p) {
      if (p == 0) {
        if (kt + 1 < KT) asm volatile("s_waitcnt vmcnt(4)" ::: "memory");
        else             asm volatile("s_waitcnt vmcnt(0)" ::: "memory");
      }
      __builtin_amdgcn_s_barrier();
      if (p == 0) {
#pragma unroll
        for (int kh = 0; kh < 2; ++kh)
#pragma unroll
          for (int j = 0; j < 4; ++j)
            bfv[kh][j] = *(const bf16x8*)(
                &LB[slot * BUF + (((kh << 2) + lg) * 256 + wn * 64 + (j << 4) + l15) * 8]);
      }
      bf16x8 af[2][2];
#pragma unroll
      for (int fl = 0; fl < 2; ++fl)
#pragma unroll
        for (int kh = 0; kh < 2; ++kh)
          af[fl][kh] = *(const bf16x8*)(
              &LA[slot * BUF + (((kh << 2) + lg) * 256 + wm * 128 + ((2 * p + fl) << 4) + l15) * 8]);

      if (p == 0 && kt + 1 < KT) STAGE_A(kt + 1, 0);
      if (p == 1 && kt + 1 < KT) STAGE_A(kt + 1, 1);
      if (p == 2 && kt + 2 < KT) STAGE_B(kt + 2, 0);
      if (p == 3 && kt + 2 < KT) STAGE_B(kt + 2, 1);

      asm volatile("s_waitcnt lgkmcnt(0)" ::: "memory");
      __builtin_amdgcn_sched_barrier(0);
      __builtin_amdgcn_s_setprio(1);
#pragma unroll
      for (int fl = 0; fl < 2; ++fl)
#pragma unroll
        for (int j = 0; j < 4; ++j)
#pragma unroll
          for (int kh = 0; kh < 2; ++kh)
            acc[2 * p + fl][j] = __builtin_amdgcn_mfma_f32_16x16x32_bf16(
                af[fl][kh], bfv[kh][j], acc[2 * p + fl][j], 0, 0, 0);
      __builtin_amdgcn_s_setprio(0);
    }
  }

#pragma unroll
  for (int i = 0; i < 8; ++i) {
#pragma unroll
    for (int j = 0; j < 4; ++j) {
#pragma unroll
      for (int r = 0; r < 4; ++r) {
        int m = m0 + wm * 128 + (i << 4) + (lg << 2) + r;
        int n = n0 + wn * 64 + (j << 4) + l15;
        float v = acc[i][j][r];
        int bb = m >> 11, tt = m & 2047;
        if (EPI == 1) {
          int h = n >> 8, d = n & 255;
          ((u16*)Op)[(((size_t)bb * NHD + h) * TSEQ + tt) * HDIM + d] = f2bf(v);
        } else {   // EPI 3: fused KV
          if (n < 2048) {
            int h = n >> 8, d = n & 255;
            ((u16*)Op)[(((size_t)bb * NKVH + h) * TSEQ + tt) * HDIM + d] = f2bf(v);
          } else {
            int n2 = n - 2048;
            int h = n2 >> 8, d = n2 & 255;
            ((u16*)Op)[8388608u + (((size_t)bb * NKVH + h) * HDIM + d) * TSEQ + tt] = f2bf(v);
          }
        }
      }
    }
  }
}

// ---------------------------------------------------------------------------
// R5 2-phase GEMM (proven) for the output projection.  BM=128.
// ---------------------------------------------------------------------------
template<int EPI, int BM>
__global__ __launch_bounds__(512, 2) void gemm256_k(
    const u16* __restrict__ Ab, const u16* __restrict__ BTp,
    void* __restrict__ Op, int M, int N, int K)
{
  constexpr int NI = BM / 32;
  constexpr int AI = BM / 64;
  __shared__ u16 LA[2][BM * 64];
  __shared__ u16 LB[2][256 * 64];
  const int t = threadIdx.x;
  const int lane = t & 63, wave = t >> 6;
  const int lg = lane >> 4, l15 = lane & 15;
  const int wm = wave >> 2, wn = wave & 3;
  const int mtiles = M / BM;
  const int mt = (int)blockIdx.x % mtiles, nt = (int)blockIdx.x / mtiles;
  const int m0 = mt * BM, n0 = nt << 8;

  const int arow = wave * (BM / 8) + (lane >> 3);
  const int ska  = ((lane & 7) ^ (arow & 7)) << 3;
  const int brow = wave * 32 + (lane >> 3);
  const int skb  = ((lane & 7) ^ (brow & 7)) << 3;
  const u16* Ag = Ab  + (size_t)(m0 + arow) * K + ska;
  const u16* Bg = BTp + (size_t)(n0 + brow) * K + skb;

  auto STAGE = [&](int k0, int sel) {
#pragma unroll
    for (int q = 0; q < AI; ++q)
      gl_lds16(Ag + k0 + (size_t)q * 8 * K, &LA[sel][(wave * (BM / 8) + q * 8) * 64]);
#pragma unroll
    for (int q = 0; q < 4; ++q)
      gl_lds16(Bg + k0 + (size_t)q * 8 * K, &LB[sel][(wave * 32 + q * 8) * 64]);
  };

  floatx4 acc[NI][4];
#pragma unroll
  for (int i = 0; i < NI; ++i)
#pragma unroll
    for (int j = 0; j < 4; ++j) acc[i][j] = (floatx4){0.f, 0.f, 0.f, 0.f};

  STAGE(0, 0);
  const int KT = K >> 6;
  for (int kt = 0; kt < KT; ++kt) {
    const int sel = kt & 1;
    if (kt + 1 < KT) {
      STAGE((kt + 1) << 6, sel ^ 1);
      if constexpr (BM == 256) asm volatile("s_waitcnt vmcnt(8)" ::: "memory");
      else                     asm volatile("s_waitcnt vmcnt(6)" ::: "memory");
    } else {
      asm volatile("s_waitcnt vmcnt(0)" ::: "memory");
    }
    __builtin_amdgcn_s_barrier();
    __builtin_amdgcn_sched_barrier(0);
    __builtin_amdgcn_s_setprio(1);
#pragma unroll
    for (int ks = 0; ks < 2; ++ks) {
      const int c = (ks << 2) + lg;
      bf16x8 bfv[4];
#pragma unroll
      for (int j = 0; j < 4; ++j) {
        int row = wn * 64 + (j << 4) + l15;
        bfv[j] = *(const bf16x8*)(&LB[sel][row * 64 + ((c ^ (row & 7)) << 3)]);
      }
#pragma unroll
      for (int i = 0; i < NI; ++i) {
        int row = wm * (BM / 2) + (i << 4) + l15;
        bf16x8 af = *(const bf16x8*)(&LA[sel][row * 64 + ((c ^ (row & 7)) << 3)]);
#pragma unroll
        for (int j = 0; j < 4; ++j)
          acc[i][j] = __builtin_amdgcn_mfma_f32_16x16x32_bf16(af, bfv[j], acc[i][j], 0, 0, 0);
      }
    }
    __builtin_amdgcn_s_setprio(0);
    __builtin_amdgcn_s_barrier();
  }

#pragma unroll
  for (int i = 0; i < NI; ++i) {
#pragma unroll
    for (int j = 0; j < 4; ++j) {
#pragma unroll
      for (int r = 0; r < 4; ++r) {
        int m = m0 + wm * (BM / 2) + (i << 4) + (lg << 2) + r;
        int n = n0 + wn * 64 + (j << 4) + l15;
        ((float*)Op)[(size_t)m * N + n] = acc[i][j][r];
      }
    }
  }
}

// ---------------------------------------------------------------------------
// RoPE in-place on Q and K (single launch): pair (d, d+128)
// ---------------------------------------------------------------------------
__global__ __launch_bounds__(256) void rope_k(u16* Qb, u16* Kb) {
  size_t idx = (size_t)blockIdx.x * 256 + threadIdx.x;
  const size_t qtot = (size_t)BATCH * NHD * TSEQ * 128;
  u16* buf;
  if (idx < qtot) buf = Qb;
  else { idx -= qtot; buf = Kb; }
  int d = (int)(idx & 127);
  size_t rest = idx >> 7;
  int tt = (int)(rest & (TSEQ - 1));
  float invf = exp2f(-(float)d * 0.103810253f);   // log2(10000)/128
  float th = (float)tt * invf;
  float sn, cs;
  sincosf(th, &sn, &cs);
  size_t base = rest * HDIM;
  float x1 = bf2f(buf[base + d]);
  float x2 = bf2f(buf[base + d + 128]);
  buf[base + d]       = f2bf(x1 * cs - x2 * sn);
  buf[base + d + 128] = f2bf(x2 * cs + x1 * sn);
}

// ---------------------------------------------------------------------------
// Causal flash attention (R5 version, unchanged).
// ---------------------------------------------------------------------------
__global__ __launch_bounds__(256, 2) void attn_k(
    const u16* __restrict__ Q, const u16* __restrict__ Kb,
    const u16* __restrict__ Vt, u16* __restrict__ Y)
{
  __shared__ u16 Ks2[2][32 * 256];
  __shared__ u16 Vs2[2][256 * 32];
  __shared__ u16 Ps[4 * 16 * 32];
  __shared__ float Ls[4][16];
  const int t = threadIdx.x, lane = t & 63, w = t >> 6;
  const int lg = lane >> 4, l15 = lane & 15;
  const int qt = 31 - (int)blockIdx.y;
  const int h = (int)blockIdx.x >> 1, b = (int)blockIdx.x & 1;
  const int hkv = h >> 1;

  const u16* Kg = Kb + ((size_t)(b * NKVH + hkv)) * TSEQ * HDIM;
  const u16* Vg = Vt + ((size_t)(b * NKVH + hkv)) * HDIM * TSEQ;

  int koff[4], voff[4];
#pragma unroll
  for (int q = 0; q < 4; ++q) {
    int krow = w * 8 + q * 2 + (lane >> 5);
    int kcc  = lane & 31;
    koff[q] = krow * 256 + ((kcc ^ (krow & 7)) << 3);
    int vd  = w * 64 + q * 16 + (lane >> 2);
    voff[q] = vd * TSEQ + (((lane & 3) ^ ((vd >> 2) & 3)) << 3);
  }

  auto STAGE = [&](int st, int sel) {
    const u16* kbase = Kg + (size_t)st * (32 * 256);
    const u16* vbase = Vg + st * 32;
#pragma unroll
    for (int q = 0; q < 4; ++q)
      gl_lds16(kbase + koff[q], &Ks2[sel][(w * 8 + q * 2) * 256]);
#pragma unroll
    for (int q = 0; q < 4; ++q)
      gl_lds16(vbase + voff[q], &Vs2[sel][(w * 64 + q * 16) * 32]);
  };

  const u16* Qg = Q + (((size_t)(b * NHD + h)) * TSEQ + qt * 64 + w * 16 + l15) * HDIM;
  bf16x8 qf[8];
#pragma unroll
  for (int ks = 0; ks < 8; ++ks) qf[ks] = *(const bf16x8*)(Qg + ks * 32 + lg * 8);

  floatx4 accY[16];
#pragma unroll
  for (int i = 0; i < 16; ++i) accY[i] = (floatx4){0.f, 0.f, 0.f, 0.f};
  float rsum = 0.f;

  const int qglob = qt * 64 + w * 16 + l15;
  const int qmaxw = qt * 64 + w * 16 + 15;
  const int nst = 2 * qt + 2;
  const int fps = (l15 ^ (l15 >> 2)) & 3;

  STAGE(0, 0);
  for (int st = 0; st < nst; ++st) {
    const int sel = st & 1;
    if (st + 1 < nst) {
      STAGE(st + 1, sel ^ 1);
      asm volatile("s_waitcnt vmcnt(8)" ::: "memory");
    } else {
      asm volatile("s_waitcnt vmcnt(0)" ::: "memory");
    }
    __builtin_amdgcn_s_barrier();
    __builtin_amdgcn_sched_barrier(0);

    if (st * 32 <= qmaxw) {
      __builtin_amdgcn_s_setprio(1);
#pragma unroll
      for (int stile = 0; stile < 2; ++stile) {
        floatx4 sa = (floatx4){0.f, 0.f, 0.f, 0.f};
#pragma unroll
        for (int ks = 0; ks < 8; ++ks) {
          int row = (stile << 4) + l15;
          int c = (ks << 2) + lg;
          bf16x8 kf = *(const bf16x8*)((const char*)Ks2[sel] +
                        row * 512 + ((c ^ (row & 7)) << 4));
          sa = __builtin_amdgcn_mfma_f32_16x16x32_bf16(kf, qf[ks], sa, 0, 0, 0);
        }
        int sbase = st * 32 + (stile << 4) + (lg << 2);
        float p[4];
#pragma unroll
        for (int r = 0; r < 4; ++r) {
          float u = fexp2(sa[r] * 0.0036067376f);
          float pv = fexp2(-144.26950408f * frcp(u + 1.0f));
          pv = (sbase + r <= qglob) ? pv : 0.0f;
          p[r] = pv;
          rsum += pv;
        }
        uint2 pw;
        pw.x = cvt2bf(p[0], p[1]);
        pw.y = cvt2bf(p[2], p[3]);
        int o = (stile << 5) + (lg << 3);
        int gran = (o >> 4) ^ fps;
        *(uint2*)((char*)Ps + (w << 10) + l15 * 64 + (gran << 4) + (o & 15)) = pw;
      }
      {
        bf16x8 pf = *(const bf16x8*)((const char*)Ps + (w << 10) + l15 * 64 +
                      ((lg ^ fps) << 4));
#pragma unroll
        for (int dt = 0; dt < 16; ++dt) {
          int row = (dt << 4) + l15;
          bf16x8 vf = *(const bf16x8*)((const char*)Vs2[sel] +
                        row * 64 + ((lg ^ ((row >> 2) & 3)) << 4));
          accY[dt] = __builtin_amdgcn_mfma_f32_16x16x32_bf16(pf, vf, accY[dt], 0, 0, 0);
        }
      }
      __builtin_amdgcn_s_setprio(0);
    }
    __builtin_amdgcn_s_barrier();
  }

  rsum += __shfl_xor(rsum, 16);
  rsum += __shfl_xor(rsum, 32);
  if (lane < 16) Ls[w][l15] = rsum;
  __syncthreads();
  float inv[4];
#pragma unroll
  for (int r = 0; r < 4; ++r) inv[r] = 1.0f / Ls[w][(lg << 2) + r];

  u16* Yg = Y + ((size_t)(b * TSEQ + qt * 64 + w * 16)) * (NHD * HDIM) + h * HDIM;
#pragma unroll
  for (int dt = 0; dt < 16; ++dt)
#pragma unroll
    for (int r = 0; r < 4; ++r)
      Yg[(size_t)((lg << 2) + r) * (NHD * HDIM) + (dt << 4) + l15] =
          f2bf(accY[dt][r] * inv[r]);
}

// ---------------------------------------------------------------------------
extern "C" void kernel_launch(void* const* d_in, const int* in_sizes, int n_in,
                              void* d_out, int out_size, void* d_ws, size_t ws_size,
                              hipStream_t stream) {
  const float* X  = (const float*)d_in[0];
  const float* Wq = (const float*)d_in[1];
  const float* Wk = (const float*)d_in[2];
  const float* Wv = (const float*)d_in[3];
  const float* Wo = (const float*)d_in[4];
  float* out = (float*)d_out;

  u16* ws   = (u16*)d_ws;
  u16* XB   = ws;                 // [4096][2048] bf16        8,388,608
  u16* WT   = ws + 8388608;       // WqT / WkvT [4096][2048]  8,388,608
  u16* Qb   = ws + 16777216;      // [B][NH][T][HD]           16,777,216
  u16* KVb  = ws + 33554432;      // K [B][NKV][T][HD] + V^T  16,777,216
  u16* Yb   = ws;                 // [B*T][NH*HD] (over XB+WT, dead by then)
  u16* WoT  = ws + 16777216;      // [2048][4096] (over Qb, dead after attn)

  dim3 blk(256);
  xconv_k<<<dim3(4096), blk, 0, stream>>>(X, XB);
  tconv_k<<<dim3(64, 32), blk, 0, stream>>>(Wq, WT, 2048, 4096);
  gemmq_k<1><<<dim3(16 * 16), dim3(512), 0, stream>>>(XB, WT, Qb, 4096, 4096, 2048);
  tconv_k<<<dim3(32, 32), blk, 0, stream>>>(Wk, WT, 2048, 2048);
  tconv_k<<<dim3(32, 32), blk, 0, stream>>>(Wv, WT + (size_t)2048 * 2048, 2048, 2048);
  gemmq_k<3><<<dim3(16 * 16), dim3(512), 0, stream>>>(XB, WT, KVb, 4096, 4096, 2048);
  rope_k<<<dim3((BATCH * (NHD + NKVH) * TSEQ * 128) / 256), blk, 0, stream>>>(Qb, KVb);
  attn_k<<<dim3(32, 32), blk, 0, stream>>>(Qb, KVb, KVb + 8388608, Yb);
  tconv_k<<<dim3(32, 64), blk, 0, stream>>>(Wo, WoT, 4096, 2048);
  gemm256_k<0, 128><<<dim3(32 * 8), dim3(512), 0, stream>>>(Yb, WoT, out, 4096, 2048, 4096);
}